// Round 1
// baseline (208.038 us; speedup 1.0000x reference)
//
#include <hip/hip_runtime.h>
#include <math.h>
#include <stdint.h>

#define NPIX 262144   // 512*512
#define BATCH 4
#define RANK 8
#define CTXD 512
#define OUTF 210
#define SA 105

// ---- workspace layout ----
// float region (offsets in floats)
#define XT_OFF   0      // xt[4][210]            (840)
#define G_OFF    864    // gated g[4][105]       (420)
#define WR_OFF   1296   // wr softmax [4][9]     (36)
#define M_OFF    1344   // M[4][8][8]            (256)
#define V_OFF    1600   // v[4][8]               (32)
#define CADD_OFF 1632   // cadd[4]               (4)
#define SC_OFF   1648   // sc[4][8]              (32)
// double region (byte offsets)
#define GRAM_BYTE 6784  // gram[4][36] doubles   (1152 B)
#define SUMS_BYTE 7936  // sums[4][16] doubles   (512 B)  [k]=sum, [8+k]=sumsq
#define ZERO_BYTE 6784
#define ZERO_LEN  1664
// big buffer
#define WFS_OFF  4096   // floats; wfs[4][8][262144] = 32 MiB

// ---------------- threefry2x32 (JAX original scheme, key=(0,42)) -------------
__device__ __forceinline__ void threefry2x32_pair(unsigned int x0, unsigned int x1,
                                                  unsigned int* o0, unsigned int* o1) {
  const unsigned int ks0 = 0u, ks1 = 42u, ks2 = 0x1BD11BF0u;  // 0^42^0x1BD11BDA
  x0 += ks0; x1 += ks1;
#define TF_R(rot) { x0 += x1; x1 = (x1 << rot) | (x1 >> (32 - rot)); x1 ^= x0; }
  TF_R(13) TF_R(15) TF_R(26) TF_R(6)
  x0 += ks1; x1 += ks2 + 1u;
  TF_R(17) TF_R(29) TF_R(16) TF_R(24)
  x0 += ks2; x1 += ks0 + 2u;
  TF_R(13) TF_R(15) TF_R(26) TF_R(6)
  x0 += ks0; x1 += ks1 + 3u;
  TF_R(17) TF_R(29) TF_R(16) TF_R(24)
  x0 += ks1; x1 += ks2 + 4u;
  TF_R(13) TF_R(15) TF_R(26) TF_R(6)
  x0 += ks2; x1 += ks0 + 5u;
#undef TF_R
  *o0 = x0; *o1 = x1;
}

// XLA ErfInv32 (Giles 2012 single-precision polynomial)
__device__ __forceinline__ float erfinv_f32(float x) {
  float w = -log1pf(-x * x);
  float p;
  if (w < 5.0f) {
    w = w - 2.5f;
    p = 2.81022636e-08f;
    p = 3.43273939e-07f + p * w;
    p = -3.5233877e-06f + p * w;
    p = -4.39150654e-06f + p * w;
    p = 0.00021858087f  + p * w;
    p = -0.00125372503f + p * w;
    p = -0.00417768164f + p * w;
    p = 0.246640727f    + p * w;
    p = 1.50140941f     + p * w;
  } else {
    w = sqrtf(w) - 3.0f;
    p = -0.000200214257f;
    p = 0.000100950558f + p * w;
    p = 0.00134934322f  + p * w;
    p = -0.00367342844f + p * w;
    p = 0.00573950773f  + p * w;
    p = -0.0076224613f  + p * w;
    p = 0.00943887047f  + p * w;
    p = 1.00167406f     + p * w;
    p = 2.83297682f     + p * w;
  }
  return p * x;
}

__device__ __forceinline__ float bits_to_normal(unsigned int bits) {
  unsigned int fb = (bits >> 9) | 0x3f800000u;
  float f = __uint_as_float(fb) - 1.0f;                 // [0,1)
  const float lo = -0.99999994039535522461f;            // nextafter(-1,0) f32
  float u = f * 2.0f + lo;                              // (hi-lo) rounds to 2.0f
  u = fmaxf(u, lo);
  return 1.4142135623730951f * erfinv_f32(u);
}

// ---------------- K1: xt = x @ ctx_w.T + ctx_b  (840 dot products) -----------
__global__ void k_xt(const float* __restrict__ x, const float* __restrict__ cw,
                     const float* __restrict__ cb, float* __restrict__ xt) {
  int bi = blockIdx.x;            // 0..839
  int b = bi / OUTF, i = bi % OUTF;
  int lane = threadIdx.x;         // 64
  const float* xr = x + b * CTXD;
  const float* wrow = cw + i * CTXD;
  double acc = 0.0;
  for (int j = lane; j < CTXD; j += 64)
    acc += (double)xr[j] * (double)wrow[j];
  for (int off = 32; off > 0; off >>= 1)
    acc += __shfl_down(acc, off, 64);
  if (lane == 0) xt[b * OUTF + i] = (float)acc + cb[i];
}

// ---------------- K2: gating + wr softmax ------------------------------------
__global__ void k_prep(float* __restrict__ ws) {
  float* xt = ws + XT_OFF;
  float* g  = ws + G_OFF;
  float* wr = ws + WR_OFF;
  int tid = threadIdx.x;
  for (int idx = tid; idx < BATCH * SA; idx += blockDim.x) {
    int b = idx / SA, i = idx % SA;
    g[b * SA + i] = xt[b * OUTF + i] * tanhf(xt[b * OUTF + SA + i]);
  }
  __syncthreads();
  if (tid < BATCH) {
    int b = tid;
    float raw[9];
    for (int j = 0; j < 9; ++j) raw[j] = g[b * SA + 96 + j];
    raw[8] += 0.35355339059327373f;  // 1/sqrt(8)
    double ss = 0.0;
    for (int j = 0; j < 9; ++j) ss += (double)raw[j] * (double)raw[j];
    float n = fmaxf((float)sqrt(ss), 1e-12f);
    float y[9]; float m = -1e30f;
    for (int j = 0; j < 9; ++j) { y[j] = raw[j] / n; m = fmaxf(m, y[j]); }
    float e[9]; double se = 0.0;
    for (int j = 0; j < 9; ++j) { e[j] = expf(y[j] - m); se += (double)e[j]; }
    for (int j = 0; j < 9; ++j) wr[b * 9 + j] = e[j] / (float)se;
  }
}

// ---------------- K3: wf (stabilized) from weights ---------------------------
__global__ __launch_bounds__(256) void k_wfs(const float* __restrict__ wts,
                                             float* __restrict__ ws) {
  const float* g = ws + G_OFF;
  float* wfs = ws + WFS_OFF;
  int gid = blockIdx.x * 256 + threadIdx.x;    // 0..1048575
  int k  = gid >> 17;                          // rank (block-uniform: 512 blocks/k)
  int pp = gid & 131071;
  int p0 = pp << 1;                            // 2 pixels per thread
  const float4* w4 = (const float4*)wts;
  // ld[s][comp] = {px0.re, px0.im, px1.re, px1.im}
  float4 ld[2][2];
#pragma unroll
  for (int s = 0; s < 2; ++s)
#pragma unroll
    for (int comp = 0; comp < 2; ++comp)
      ld[s][comp] = w4[(((k * 4 + s * 2 + comp) << 18) + p0) >> 1];

#pragma unroll
  for (int b = 0; b < BATCH; ++b) {
    const float* gb = g + b * SA + 12 * k;
    float zr[2][2], zi[2][2];   // [comp][pixel]
#pragma unroll
    for (int comp = 0; comp < 2; ++comp) {
      float c0 = gb[2 * comp]     + 0.5f;
      float c1 = gb[2 * comp + 1];
      float b0 = gb[4 + 2 * comp];
      float b1 = gb[5 + 2 * comp];
      float s0 = gb[8 + 2 * comp] + 1.0f;
      float s1 = gb[9 + 2 * comp];
      float4 W0 = ld[0][comp], W1 = ld[1][comp];
#pragma unroll
      for (int j = 0; j < 2; ++j) {
        float w0r = j ? W0.z : W0.x;
        float w0i = j ? W0.w : W0.y;
        float w1r = j ? W1.z : W1.x;
        float w1i = j ? W1.w : W1.y;
        float dr = w1r - w0r, di = w1i - w0i;
        float lr = w0r + c0 * dr - c1 * di;
        float li = w0i + c0 * di + c1 * dr;
        zr[comp][j] = b0 + lr * s0 - li * s1;
        zi[comp][j] = b1 + lr * s1 + li * s0;
      }
    }
    float2 st;
#pragma unroll
    for (int j = 0; j < 2; ++j) {
      float d2 = zr[1][j] * zr[1][j] + zi[1][j] * zi[1][j];
      float dn = sqrtf(fmaxf(d2, 1e-12f));
      float thr = zr[1][j] / dn, thi = zi[1][j] / dn;
      float w = zr[0][j] * thr + zi[0][j] * thi;
      if (fabsf(w) < 1e-12f) w = (w > 0.f) ? 1e-12f : ((w < 0.f) ? -1e-12f : 0.f);
      if (j) st.y = w; else st.x = w;
    }
    *reinterpret_cast<float2*>(wfs + ((b * RANK + k) << 18) + p0) = st;
  }
}

// ---------------- K4: Gram matrix (upper-tri incl. diag, 36/batch) -----------
__global__ __launch_bounds__(256) void k_gram(void* wsv) {
  float* ws = (float*)wsv;
  const float* wfs = ws + WFS_OFF;
  double* gram = (double*)((char*)wsv + GRAM_BYTE);
  int b = blockIdx.x >> 8;                 // 256 blocks per batch
  int chunk = blockIdx.x & 255;
  int p0 = (chunk * 256 + threadIdx.x) * 4;
  float4 v[8];
#pragma unroll
  for (int s = 0; s < 8; ++s)
    v[s] = *reinterpret_cast<const float4*>(wfs + ((b * RANK + s) << 18) + p0);
  float prod[36];
  {
    int idx = 0;
#pragma unroll
    for (int r = 0; r < 8; ++r)
#pragma unroll
      for (int s = r; s < 8; ++s, ++idx)
        prod[idx] = v[r].x * v[s].x + v[r].y * v[s].y + v[r].z * v[s].z + v[r].w * v[s].w;
  }
  __shared__ double lds[4][36];
  int lane = threadIdx.x & 63, wv = threadIdx.x >> 6;
#pragma unroll
  for (int i = 0; i < 36; ++i) {
    double d = (double)prod[i];
    for (int off = 32; off > 0; off >>= 1) d += __shfl_down(d, off, 64);
    if (lane == 0) lds[wv][i] = d;
  }
  __syncthreads();
  if (threadIdx.x < 36) {
    double t = lds[0][threadIdx.x] + lds[1][threadIdx.x] +
               lds[2][threadIdx.x] + lds[3][threadIdx.x];
    atomicAdd(&gram[b * 36 + threadIdx.x], t);
  }
}

// ---------------- K5: norms + repulsion mix matrix M -------------------------
__global__ void k_prep2(void* wsv) {
  float* ws = (float*)wsv;
  double* gram = (double*)((char*)wsv + GRAM_BYTE);
  float* M = ws + M_OFF;
  __shared__ float norm1[BATCH][RANK];
  int tid = threadIdx.x;  // 64
  if (tid < 32) {
    int b = tid >> 3, k = tid & 7;
    int di = k * 8 - (k * (k - 1)) / 2;      // (k,k) in upper-tri
    norm1[b][k] = fmaxf((float)sqrt(gram[b * 36 + di]), 1e-12f);
  }
  __syncthreads();
  for (int idx = tid; idx < 256; idx += blockDim.x) {
    int b = idx >> 6, k = (idx >> 3) & 7, s = idx & 7;
    float m;
    if (k == s) {
      m = 1.0f / norm1[b][k];
    } else {
      int r0 = k < s ? k : s, s0 = k < s ? s : k;
      int gi = r0 * 8 - (r0 * (r0 - 1)) / 2 + (s0 - r0);
      float simv = (float)(gram[b * 36 + gi] / ((double)norm1[b][k] * (double)norm1[b][s]));
      m = -0.0050507627227610544f * simv / norm1[b][s];  // (0.1/sqrt(8))/7
    }
    M[b * 64 + k * 8 + s] = m;
  }
}

// ---------------- K6: sum/sumsq of stabilized wf2 = M @ wf -------------------
__global__ __launch_bounds__(256) void k_sums(void* wsv) {
  float* ws = (float*)wsv;
  const float* wfs = ws + WFS_OFF;
  const float* M = ws + M_OFF;
  double* sums = (double*)((char*)wsv + SUMS_BYTE);  // [b][16]
  int b = blockIdx.x >> 8;
  int chunk = blockIdx.x & 255;
  int p0 = (chunk * 256 + threadIdx.x) * 4;
  float4 v[8];
#pragma unroll
  for (int s = 0; s < 8; ++s)
    v[s] = *reinterpret_cast<const float4*>(wfs + ((b * RANK + s) << 18) + p0);
  double accs[8], accq[8];
#pragma unroll
  for (int k = 0; k < 8; ++k) {
    float ax = 0.f, ay = 0.f, az = 0.f, aw = 0.f;
#pragma unroll
    for (int s = 0; s < 8; ++s) {
      float m = M[b * 64 + k * 8 + s];
      ax += m * v[s].x; ay += m * v[s].y; az += m * v[s].z; aw += m * v[s].w;
    }
    // _stable
    if (fabsf(ax) < 1e-12f) ax = (ax > 0.f) ? 1e-12f : ((ax < 0.f) ? -1e-12f : 0.f);
    if (fabsf(ay) < 1e-12f) ay = (ay > 0.f) ? 1e-12f : ((ay < 0.f) ? -1e-12f : 0.f);
    if (fabsf(az) < 1e-12f) az = (az > 0.f) ? 1e-12f : ((az < 0.f) ? -1e-12f : 0.f);
    if (fabsf(aw) < 1e-12f) aw = (aw > 0.f) ? 1e-12f : ((aw < 0.f) ? -1e-12f : 0.f);
    accs[k] = (double)ax + (double)ay + (double)az + (double)aw;
    accq[k] = (double)ax * ax + (double)ay * ay + (double)az * az + (double)aw * aw;
  }
  __shared__ double lds[4][16];
  int lane = threadIdx.x & 63, wv = threadIdx.x >> 6;
#pragma unroll
  for (int i = 0; i < 16; ++i) {
    double d = (i < 8) ? accs[i] : accq[i - 8];
    for (int off = 32; off > 0; off >>= 1) d += __shfl_down(d, off, 64);
    if (lane == 0) lds[wv][i] = d;
  }
  __syncthreads();
  if (threadIdx.x < 16) {
    double t = lds[0][threadIdx.x] + lds[1][threadIdx.x] +
               lds[2][threadIdx.x] + lds[3][threadIdx.x];
    atomicAdd(&sums[b * 16 + threadIdx.x], t);
  }
}

// ---------------- K7: norm2/mean/std -> folded coefficients ------------------
__global__ void k_prep3(void* wsv) {
  float* ws = (float*)wsv;
  double* sums = (double*)((char*)wsv + SUMS_BYTE);
  const float* M = ws + M_OFF;
  const float* wr = ws + WR_OFF;
  float* v = ws + V_OFF;
  float* cadd = ws + CADD_OFF;
  float* sc = ws + SC_OFF;
  __shared__ float inorm2[BATCH][RANK], meanv[BATCH][RANK], stdv[BATCH][RANK];
  int tid = threadIdx.x;  // 64
  if (tid < 32) {
    int b = tid >> 3, k = tid & 7;
    double sum = sums[b * 16 + k], sq = sums[b * 16 + 8 + k];
    double n2 = sqrt(sq); if (n2 < 1e-12) n2 = 1e-12;
    double mean = sum / n2 / (double)NPIX;
    double sy2 = sq / (n2 * n2);
    double var = (sy2 - (double)NPIX * mean * mean) / (double)(NPIX - 1);
    if (var < 0.0) var = 0.0;
    double sd = sqrt(var); if (sd < 1e-12) sd = 1e-12;
    inorm2[b][k] = (float)(1.0 / n2);
    meanv[b][k] = (float)mean;
    stdv[b][k] = (float)sd;
  }
  __syncthreads();
  if (tid < 32) {
    int b = tid >> 3, s = tid & 7;
    float acc = 0.f;
    for (int k = 0; k < 8; ++k)
      acc += wr[b * 9 + k] * M[b * 64 + k * 8 + s] * inorm2[b][k];
    v[b * 8 + s] = acc;
    sc[b * 8 + s] = wr[b * 9 + s] * 0.01f * stdv[b][s];
  }
  if (tid < 4) {
    float a = 0.f;
    for (int k = 0; k < 8; ++k) a += wr[tid * 9 + k] * 0.01f * meanv[tid][k];
    cadd[tid] = a;
  }
}

// ---------------- K8: output = v . wf + cadd + noise terms -------------------
__global__ __launch_bounds__(256) void k_out(void* wsv, float* __restrict__ out) {
  float* ws = (float*)wsv;
  const float* wfs = ws + WFS_OFF;
  const float* v = ws + V_OFF;
  const float* cadd = ws + CADD_OFF;
  const float* sc = ws + SC_OFF;
  int p = blockIdx.x * 256 + threadIdx.x;  // < 262144
  float o[4];
#pragma unroll
  for (int b = 0; b < 4; ++b) {
    float acc = cadd[b];
#pragma unroll
    for (int s = 0; s < 8; ++s)
      acc += v[b * 8 + s] * wfs[((b * RANK + s) << 18) + p];
    o[b] = acc;
  }
  // noise: flat index j=(b*8+k)*NPIX+p; pairs (j, j+2^22) share one threefry block
#pragma unroll
  for (int bk = 0; bk < 16; ++bk) {
    unsigned int i = ((unsigned int)bk << 18) + (unsigned int)p;
    unsigned int r0, r1;
    threefry2x32_pair(i, i + 0x400000u, &r0, &r1);
    int b2 = bk >> 3, k = bk & 7;
    o[b2]     += sc[b2 * 8 + k]       * bits_to_normal(r0);
    o[b2 + 2] += sc[(b2 + 2) * 8 + k] * bits_to_normal(r1);
  }
#pragma unroll
  for (int b = 0; b < 4; ++b) out[(b << 18) + p] = o[b];
}

extern "C" void kernel_launch(void* const* d_in, const int* in_sizes, int n_in,
                              void* d_out, int out_size, void* d_ws, size_t ws_size,
                              hipStream_t stream) {
  const float* x   = (const float*)d_in[0];
  const float* cw  = (const float*)d_in[1];
  const float* cb  = (const float*)d_in[2];
  const float* wts = (const float*)d_in[3];
  float* out = (float*)d_out;
  float* ws  = (float*)d_ws;

  // zero the double accumulators (ws is re-poisoned to 0xAA before every launch)
  hipMemsetAsync((char*)d_ws + ZERO_BYTE, 0, ZERO_LEN, stream);

  k_xt   <<<840,  64,  0, stream>>>(x, cw, cb, ws + XT_OFF);
  k_prep <<<1,    128, 0, stream>>>(ws);
  k_wfs  <<<4096, 256, 0, stream>>>(wts, ws);
  k_gram <<<1024, 256, 0, stream>>>(d_ws);
  k_prep2<<<1,    64,  0, stream>>>(d_ws);
  k_sums <<<1024, 256, 0, stream>>>(d_ws);
  k_prep3<<<1,    64,  0, stream>>>(d_ws);
  k_out  <<<1024, 256, 0, stream>>>(d_ws, out);
}

// Round 2
// 204.099 us; speedup vs baseline: 1.0193x; 1.0193x over previous
//
#include <hip/hip_runtime.h>
#include <math.h>

#define NPIX 262144   // 512*512
#define BATCH 4
#define RANK 8
#define CTXD 512
#define OUTF 210
#define SA 105

// ---- workspace layout (float offsets) ----
#define G_OFF    864    // gated g[4][105]
#define WR_OFF   1296   // wr softmax [4][9]
#define GRAM_OFF 1344   // float gram[4][36]  (atomics, zeroed per call)
#define SUMS_OFF 1488   // float sums[4][16]  ([k]=sum, [8+k]=sumsq)
#define WFS_OFF  4096   // wfs[4][8][262144] = 32 MiB
#define ZERO_BYTE (GRAM_OFF * 4)
#define ZERO_LEN  ((SUMS_OFF + 64 - GRAM_OFF) * 4)

// ---------------- wave64 sum via DPP (result in lane 63) ---------------------
__device__ __forceinline__ float dpp_sum64(float x) {
  x += __int_as_float(__builtin_amdgcn_update_dpp(0, __float_as_int(x), 0x111, 0xf, 0xf, true)); // row_shr:1
  x += __int_as_float(__builtin_amdgcn_update_dpp(0, __float_as_int(x), 0x112, 0xf, 0xf, true)); // row_shr:2
  x += __int_as_float(__builtin_amdgcn_update_dpp(0, __float_as_int(x), 0x114, 0xf, 0xf, true)); // row_shr:4
  x += __int_as_float(__builtin_amdgcn_update_dpp(0, __float_as_int(x), 0x118, 0xf, 0xf, true)); // row_shr:8
  x += __int_as_float(__builtin_amdgcn_update_dpp(0, __float_as_int(x), 0x142, 0xf, 0xf, true)); // row_bcast:15
  x += __int_as_float(__builtin_amdgcn_update_dpp(0, __float_as_int(x), 0x143, 0xf, 0xf, true)); // row_bcast:31
  return x;
}

// ---------------- threefry2x32 (JAX original scheme, key=(0,42)) -------------
__device__ __forceinline__ void threefry2x32_pair(unsigned int x0, unsigned int x1,
                                                  unsigned int* o0, unsigned int* o1) {
  const unsigned int ks0 = 0u, ks1 = 42u, ks2 = 0x1BD11BF0u;
  x0 += ks0; x1 += ks1;
#define TF_R(rot) { x0 += x1; x1 = (x1 << rot) | (x1 >> (32 - rot)); x1 ^= x0; }
  TF_R(13) TF_R(15) TF_R(26) TF_R(6)
  x0 += ks1; x1 += ks2 + 1u;
  TF_R(17) TF_R(29) TF_R(16) TF_R(24)
  x0 += ks2; x1 += ks0 + 2u;
  TF_R(13) TF_R(15) TF_R(26) TF_R(6)
  x0 += ks0; x1 += ks1 + 3u;
  TF_R(17) TF_R(29) TF_R(16) TF_R(24)
  x0 += ks1; x1 += ks2 + 4u;
  TF_R(13) TF_R(15) TF_R(26) TF_R(6)
  x0 += ks2; x1 += ks0 + 5u;
#undef TF_R
  *o0 = x0; *o1 = x1;
}

// bits -> uniform(-1,1) -> sqrt(2)*erfinv (Giles poly, fast log path).
// Noise enters the output scaled by ~2.4e-6, so a few-ulp log/sqrt is plenty.
__device__ __forceinline__ float fast_normal(unsigned int bits) {
  unsigned int fb = (bits >> 9) | 0x3f800000u;
  float f = __uint_as_float(fb) - 1.0f;                 // [0,1)
  const float lo = -0.99999994039535522461f;            // nextafter(-1,0) f32
  float u = f * 2.0f + lo;
  u = fmaxf(u, lo);
  float w = -__logf(fmaf(-u, u, 1.0f));                 // -log(1-u^2), single-round 1-u^2
  float q1 = w - 2.5f;
  float p1 = 2.81022636e-08f;
  p1 = fmaf(p1, q1, 3.43273939e-07f);
  p1 = fmaf(p1, q1, -3.5233877e-06f);
  p1 = fmaf(p1, q1, -4.39150654e-06f);
  p1 = fmaf(p1, q1, 0.00021858087f);
  p1 = fmaf(p1, q1, -0.00125372503f);
  p1 = fmaf(p1, q1, -0.00417768164f);
  p1 = fmaf(p1, q1, 0.246640727f);
  p1 = fmaf(p1, q1, 1.50140941f);
  float q2 = sqrtf(w) - 3.0f;
  float p2 = -0.000200214257f;
  p2 = fmaf(p2, q2, 0.000100950558f);
  p2 = fmaf(p2, q2, 0.00134934322f);
  p2 = fmaf(p2, q2, -0.00367342844f);
  p2 = fmaf(p2, q2, 0.00573950773f);
  p2 = fmaf(p2, q2, -0.0076224613f);
  p2 = fmaf(p2, q2, 0.00943887047f);
  p2 = fmaf(p2, q2, 1.00167406f);
  p2 = fmaf(p2, q2, 2.83297682f);
  float pr = (w < 5.0f) ? p1 : p2;
  return 1.4142135623730951f * pr * u;
}

// ---------------- K1: ctx MLP + gating + wr softmax (one block) --------------
__global__ __launch_bounds__(1024) void k_ctx(const float* __restrict__ x,
                                              const float* __restrict__ cw,
                                              const float* __restrict__ cb,
                                              float* __restrict__ ws) {
  __shared__ float xl[BATCH * CTXD];
  __shared__ float xt[BATCH * OUTF];
  __shared__ float gl[BATCH * SA];
  int t = threadIdx.x;
  for (int i = t; i < BATCH * CTXD; i += 1024) xl[i] = x[i];
  __syncthreads();
  int lane = t & 63, wv = t >> 6;
  for (int oi = wv; oi < BATCH * OUTF; oi += 16) {
    int b = oi / OUTF, i = oi - b * OUTF;
    const float* wrow = cw + i * CTXD;
    float acc = 0.f;
#pragma unroll
    for (int j = 0; j < CTXD; j += 64)
      acc = fmaf(wrow[j + lane], xl[b * CTXD + j + lane], acc);
    acc = dpp_sum64(acc);
    if (lane == 63) xt[oi] = acc + cb[i];
  }
  __syncthreads();
  float* g = ws + G_OFF;
  for (int i = t; i < BATCH * SA; i += 1024) {
    int b = i / SA, j = i - b * SA;
    float v = xt[b * OUTF + j] * tanhf(xt[b * OUTF + SA + j]);
    gl[i] = v;
    g[i] = v;
  }
  __syncthreads();
  if (t < BATCH) {
    int b = t;
    float* wr = ws + WR_OFF;
    float raw[9];
    for (int j = 0; j < 9; ++j) raw[j] = gl[b * SA + 96 + j];
    raw[8] += 0.35355339059327373f;  // 1/sqrt(8)
    double ss = 0.0;
    for (int j = 0; j < 9; ++j) ss += (double)raw[j] * (double)raw[j];
    float n = fmaxf((float)sqrt(ss), 1e-12f);
    float y[9]; float m = -1e30f;
    for (int j = 0; j < 9; ++j) { y[j] = raw[j] / n; m = fmaxf(m, y[j]); }
    float e[9]; double se = 0.0;
    for (int j = 0; j < 9; ++j) { e[j] = expf(y[j] - m); se += (double)e[j]; }
    for (int j = 0; j < 9; ++j) wr[b * 9 + j] = e[j] / (float)se;
  }
}

// ---------------- K2: wf compute+store, fused Gram accumulation --------------
__global__ __launch_bounds__(256, 2) void k_wfsg(const float* __restrict__ wts,
                                                 float* __restrict__ ws) {
  const float* g = ws + G_OFF;
  float* wfs = ws + WFS_OFF;
  float* gram = ws + GRAM_OFF;
  int t = blockIdx.x * 256 + threadIdx.x;   // 0..131071
  int p0 = t << 1;                          // 2 pixels/thread
  const float4* w4 = (const float4*)wts;
  float wf[BATCH][RANK][2];
#pragma unroll
  for (int k = 0; k < RANK; ++k) {
    float4 ld[2][2];   // [s][comp] = {px0.re, px0.im, px1.re, px1.im}
#pragma unroll
    for (int s = 0; s < 2; ++s)
#pragma unroll
      for (int comp = 0; comp < 2; ++comp)
        ld[s][comp] = w4[(((k * 4 + s * 2 + comp) << 18) + p0) >> 1];
#pragma unroll
    for (int b = 0; b < BATCH; ++b) {
      const float* gb = g + b * SA + 12 * k;
      float zr[2][2], zi[2][2];
#pragma unroll
      for (int comp = 0; comp < 2; ++comp) {
        float c0 = gb[2 * comp] + 0.5f;
        float c1 = gb[2 * comp + 1];
        float b0 = gb[4 + 2 * comp];
        float b1 = gb[5 + 2 * comp];
        float s0 = gb[8 + 2 * comp] + 1.0f;
        float s1 = gb[9 + 2 * comp];
        float4 W0 = ld[0][comp], W1 = ld[1][comp];
#pragma unroll
        for (int j = 0; j < 2; ++j) {
          float w0r = j ? W0.z : W0.x;
          float w0i = j ? W0.w : W0.y;
          float w1r = j ? W1.z : W1.x;
          float w1i = j ? W1.w : W1.y;
          float dr = w1r - w0r, di = w1i - w0i;
          float lr = w0r + c0 * dr - c1 * di;
          float li = w0i + c0 * di + c1 * dr;
          zr[comp][j] = b0 + lr * s0 - li * s1;
          zi[comp][j] = b1 + lr * s1 + li * s0;
        }
      }
      float2 st;
#pragma unroll
      for (int j = 0; j < 2; ++j) {
        float d2 = zr[1][j] * zr[1][j] + zi[1][j] * zi[1][j];
        float dn = sqrtf(fmaxf(d2, 1e-12f));
        float thr = zr[1][j] / dn, thi = zi[1][j] / dn;
        float w = zr[0][j] * thr + zi[0][j] * thi;
        if (fabsf(w) < 1e-12f) w = (w > 0.f) ? 1e-12f : ((w < 0.f) ? -1e-12f : 0.f);
        wf[b][k][j] = w;
        if (j) st.y = w; else st.x = w;
      }
      *reinterpret_cast<float2*>(wfs + ((b * RANK + k) << 18) + p0) = st;
    }
  }
  // Gram: 4 batches x 36 upper-tri pairs, DPP wave-reduce then block combine
  __shared__ float gred[4][BATCH][36];
  int lane = threadIdx.x & 63, wv = threadIdx.x >> 6;
#pragma unroll
  for (int b = 0; b < BATCH; ++b) {
    int idx = 0;
#pragma unroll
    for (int r = 0; r < RANK; ++r)
#pragma unroll
      for (int s = r; s < RANK; ++s, ++idx) {
        float pr = wf[b][r][0] * wf[b][s][0] + wf[b][r][1] * wf[b][s][1];
        pr = dpp_sum64(pr);
        if (lane == 63) gred[wv][b][idx] = pr;
      }
  }
  __syncthreads();
  if (threadIdx.x < BATCH * 36) {
    int b = threadIdx.x / 36, idx = threadIdx.x - b * 36;
    float s = gred[0][b][idx] + gred[1][b][idx] + gred[2][b][idx] + gred[3][b][idx];
    atomicAdd(&gram[b * 36 + idx], s);
  }
}

// ---------------- K3: sum/sumsq of stabilized wf2 = M @ wf -------------------
// (M recomputed per block from gram — no separate prep kernel)
__global__ __launch_bounds__(256) void k_sums(float* __restrict__ ws) {
  const float* wfs = ws + WFS_OFF;
  const float* gram = ws + GRAM_OFF;
  float* sums = ws + SUMS_OFF;
  __shared__ float n1[32], Ml[256], red[4][16];
  int t = threadIdx.x;
  if (t < 32) {
    int b = t >> 3, k = t & 7;
    int di = k * 8 - (k * (k - 1)) / 2;
    n1[t] = fmaxf(sqrtf(gram[b * 36 + di]), 1e-12f);
  }
  __syncthreads();
  {
    int b = t >> 6, k = (t >> 3) & 7, s = t & 7;
    float m;
    if (k == s) {
      m = 1.0f / n1[b * 8 + k];
    } else {
      int r0 = k < s ? k : s, s0 = k < s ? s : k;
      int gi = r0 * 8 - (r0 * (r0 - 1)) / 2 + (s0 - r0);
      float simv = gram[b * 36 + gi] / (n1[b * 8 + k] * n1[b * 8 + s]);
      m = -0.0050507627227610544f * simv / n1[b * 8 + s];  // (0.1/sqrt(8))/7
    }
    Ml[t] = m;
  }
  __syncthreads();
  int b = blockIdx.x >> 8, chunk = blockIdx.x & 255;
  int p0 = (chunk * 256 + t) * 4;
  float4 v4[8];
#pragma unroll
  for (int s = 0; s < 8; ++s)
    v4[s] = *reinterpret_cast<const float4*>(wfs + ((b * RANK + s) << 18) + p0);
  float accs[8], accq[8];
#pragma unroll
  for (int k = 0; k < 8; ++k) {
    float ax = 0.f, ay = 0.f, az = 0.f, aw = 0.f;
#pragma unroll
    for (int s = 0; s < 8; ++s) {
      float m = Ml[b * 64 + k * 8 + s];
      ax += m * v4[s].x; ay += m * v4[s].y; az += m * v4[s].z; aw += m * v4[s].w;
    }
    if (fabsf(ax) < 1e-12f) ax = (ax > 0.f) ? 1e-12f : ((ax < 0.f) ? -1e-12f : 0.f);
    if (fabsf(ay) < 1e-12f) ay = (ay > 0.f) ? 1e-12f : ((ay < 0.f) ? -1e-12f : 0.f);
    if (fabsf(az) < 1e-12f) az = (az > 0.f) ? 1e-12f : ((az < 0.f) ? -1e-12f : 0.f);
    if (fabsf(aw) < 1e-12f) aw = (aw > 0.f) ? 1e-12f : ((aw < 0.f) ? -1e-12f : 0.f);
    accs[k] = (ax + ay) + (az + aw);
    accq[k] = ax * ax + ay * ay + az * az + aw * aw;
  }
  int lane = t & 63, wv = t >> 6;
#pragma unroll
  for (int i = 0; i < 16; ++i) {
    float d = (i < 8) ? accs[i] : accq[i - 8];
    d = dpp_sum64(d);
    if (lane == 63) red[wv][i] = d;
  }
  __syncthreads();
  if (t < 16) {
    float s = red[0][t] + red[1][t] + red[2][t] + red[3][t];
    atomicAdd(&sums[b * 16 + t], s);
  }
}

// ---------------- K4: output (v/sc/cadd recomputed per block) ----------------
__global__ __launch_bounds__(256) void k_out(const float* __restrict__ ws,
                                             float* __restrict__ out) {
  const float* wfs = ws + WFS_OFF;
  const float* gram = ws + GRAM_OFF;
  const float* sums = ws + SUMS_OFF;
  const float* wr = ws + WR_OFF;
  __shared__ float n1[32], Ml[256], in2[32], mnv[32], sdv[32], vv[32], scl[32], ca[4];
  int t = threadIdx.x;
  if (t < 32) {
    int b = t >> 3, k = t & 7;
    int di = k * 8 - (k * (k - 1)) / 2;
    n1[t] = fmaxf(sqrtf(gram[b * 36 + di]), 1e-12f);
  }
  __syncthreads();
  {
    int b = t >> 6, k = (t >> 3) & 7, s = t & 7;
    float m;
    if (k == s) {
      m = 1.0f / n1[b * 8 + k];
    } else {
      int r0 = k < s ? k : s, s0 = k < s ? s : k;
      int gi = r0 * 8 - (r0 * (r0 - 1)) / 2 + (s0 - r0);
      float simv = gram[b * 36 + gi] / (n1[b * 8 + k] * n1[b * 8 + s]);
      m = -0.0050507627227610544f * simv / n1[b * 8 + s];
    }
    Ml[t] = m;
  }
  if (t < 32) {
    int b = t >> 3, k = t & 7;
    float sum = sums[b * 16 + k], sq = sums[b * 16 + 8 + k];
    float n2 = fmaxf(sqrtf(sq), 1e-12f);
    float mean = sum / n2 * (1.0f / NPIX);
    float sy2 = sq / (n2 * n2);
    float var = (sy2 - (float)NPIX * mean * mean) * (1.0f / (float)(NPIX - 1));
    var = fmaxf(var, 0.f);
    float sd = fmaxf(sqrtf(var), 1e-12f);
    in2[t] = 1.f / n2; mnv[t] = mean; sdv[t] = sd;
  }
  __syncthreads();
  if (t < 32) {
    int b = t >> 3, s = t & 7;
    float acc = 0.f;
#pragma unroll
    for (int k = 0; k < 8; ++k)
      acc += wr[b * 9 + k] * Ml[b * 64 + k * 8 + s] * in2[b * 8 + k];
    vv[t] = acc;
    scl[t] = wr[b * 9 + s] * 0.01f * sdv[t];
  }
  if (t < 4) {
    float a = 0.f;
#pragma unroll
    for (int k = 0; k < 8; ++k) a += wr[t * 9 + k] * 0.01f * mnv[t * 8 + k];
    ca[t] = a;
  }
  __syncthreads();
  int p = blockIdx.x * 256 + t;
  float o[4];
#pragma unroll
  for (int b = 0; b < 4; ++b) {
    float acc = ca[b];
#pragma unroll
    for (int s = 0; s < 8; ++s)
      acc += vv[b * 8 + s] * wfs[((b * RANK + s) << 18) + p];
    o[b] = acc;
  }
  // noise: flat j=(b*8+k)*NPIX+p; pairs (j, j+2^22) share one threefry block
#pragma unroll
  for (int bk = 0; bk < 16; ++bk) {
    unsigned int i = ((unsigned int)bk << 18) + (unsigned int)p;
    unsigned int r0, r1;
    threefry2x32_pair(i, i + 0x400000u, &r0, &r1);
    int b2 = bk >> 3, k = bk & 7;
    o[b2]     += scl[b2 * 8 + k]       * fast_normal(r0);
    o[b2 + 2] += scl[(b2 + 2) * 8 + k] * fast_normal(r1);
  }
#pragma unroll
  for (int b = 0; b < 4; ++b) out[(b << 18) + p] = o[b];
}

extern "C" void kernel_launch(void* const* d_in, const int* in_sizes, int n_in,
                              void* d_out, int out_size, void* d_ws, size_t ws_size,
                              hipStream_t stream) {
  const float* x   = (const float*)d_in[0];
  const float* cw  = (const float*)d_in[1];
  const float* cb  = (const float*)d_in[2];
  const float* wts = (const float*)d_in[3];
  float* out = (float*)d_out;
  float* ws  = (float*)d_ws;

  hipMemsetAsync((char*)d_ws + ZERO_BYTE, 0, ZERO_LEN, stream);

  k_ctx  <<<1,    1024, 0, stream>>>(x, cw, cb, ws);
  k_wfsg <<<512,  256,  0, stream>>>(wts, ws);
  k_sums <<<1024, 256,  0, stream>>>(ws);
  k_out  <<<1024, 256,  0, stream>>>(ws, out);
}

// Round 4
// 150.120 us; speedup vs baseline: 1.3858x; 1.3596x over previous
//
#include <hip/hip_runtime.h>
#include <math.h>

#define NPIX 262144   // 512*512
#define BATCH 4
#define RANK 8
#define CTXD 512
#define OUTF 210

// ---- workspace layout (float offsets) ----
#define XT_OFF   0      // xt[4][210] (840 floats)
#define ACC_OFF  1024   // 8 replicas x 176 accumulators (gram[4][36], S[4][8])
#define REP      8
#define NACC     176
#define WFS_OFF  4096   // wfs[4][8][262144] = 32 MiB (byte 16384)
#define ZERO_BYTE (ACC_OFF * 4)
#define ZERO_LEN  (REP * NACC * 4)

// ---------------- wave64 sum via DPP (result in lane 63) ---------------------
__device__ __forceinline__ float dpp_sum64(float x) {
  x += __int_as_float(__builtin_amdgcn_update_dpp(0, __float_as_int(x), 0x111, 0xf, 0xf, true)); // row_shr:1
  x += __int_as_float(__builtin_amdgcn_update_dpp(0, __float_as_int(x), 0x112, 0xf, 0xf, true)); // row_shr:2
  x += __int_as_float(__builtin_amdgcn_update_dpp(0, __float_as_int(x), 0x114, 0xf, 0xf, true)); // row_shr:4
  x += __int_as_float(__builtin_amdgcn_update_dpp(0, __float_as_int(x), 0x118, 0xf, 0xf, true)); // row_shr:8
  x += __int_as_float(__builtin_amdgcn_update_dpp(0, __float_as_int(x), 0x142, 0xf, 0xf, true)); // row_bcast:15
  x += __int_as_float(__builtin_amdgcn_update_dpp(0, __float_as_int(x), 0x143, 0xf, 0xf, true)); // row_bcast:31
  return x;
}

// ---------------- threefry2x32 (JAX original scheme, key=(0,42)) -------------
__device__ __forceinline__ void threefry2x32_pair(unsigned int x0, unsigned int x1,
                                                  unsigned int* o0, unsigned int* o1) {
  const unsigned int ks0 = 0u, ks1 = 42u, ks2 = 0x1BD11BF0u;
  x0 += ks0; x1 += ks1;
#define TF_R(rot) { x0 += x1; x1 = (x1 << rot) | (x1 >> (32 - rot)); x1 ^= x0; }
  TF_R(13) TF_R(15) TF_R(26) TF_R(6)
  x0 += ks1; x1 += ks2 + 1u;
  TF_R(17) TF_R(29) TF_R(16) TF_R(24)
  x0 += ks2; x1 += ks0 + 2u;
  TF_R(13) TF_R(15) TF_R(26) TF_R(6)
  x0 += ks0; x1 += ks1 + 3u;
  TF_R(17) TF_R(29) TF_R(16) TF_R(24)
  x0 += ks1; x1 += ks2 + 4u;
  TF_R(13) TF_R(15) TF_R(26) TF_R(6)
  x0 += ks2; x1 += ks0 + 5u;
#undef TF_R
  *o0 = x0; *o1 = x1;
}

// bits -> uniform(-1,1) -> sqrt(2)*erfinv (Giles poly, fast log path).
// Noise enters the output scaled by wr*0.01*std (~1e-10 here), so few-ulp is plenty.
__device__ __forceinline__ float fast_normal(unsigned int bits) {
  unsigned int fb = (bits >> 9) | 0x3f800000u;
  float f = __uint_as_float(fb) - 1.0f;                 // [0,1)
  const float lo = -0.99999994039535522461f;            // nextafter(-1,0) f32
  float u = f * 2.0f + lo;
  u = fmaxf(u, lo);
  float w = -__logf(fmaf(-u, u, 1.0f));                 // -log(1-u^2)
  float q1 = w - 2.5f;
  float p1 = 2.81022636e-08f;
  p1 = fmaf(p1, q1, 3.43273939e-07f);
  p1 = fmaf(p1, q1, -3.5233877e-06f);
  p1 = fmaf(p1, q1, -4.39150654e-06f);
  p1 = fmaf(p1, q1, 0.00021858087f);
  p1 = fmaf(p1, q1, -0.00125372503f);
  p1 = fmaf(p1, q1, -0.00417768164f);
  p1 = fmaf(p1, q1, 0.246640727f);
  p1 = fmaf(p1, q1, 1.50140941f);
  float q2 = sqrtf(w) - 3.0f;
  float p2 = -0.000200214257f;
  p2 = fmaf(p2, q2, 0.000100950558f);
  p2 = fmaf(p2, q2, 0.00134934322f);
  p2 = fmaf(p2, q2, -0.00367342844f);
  p2 = fmaf(p2, q2, 0.00573950773f);
  p2 = fmaf(p2, q2, -0.0076224613f);
  p2 = fmaf(p2, q2, 0.00943887047f);
  p2 = fmaf(p2, q2, 1.00167406f);
  p2 = fmaf(p2, q2, 2.83297682f);
  float pr = (w < 5.0f) ? p1 : p2;
  return 1.4142135623730951f * pr * u;
}

// ---------------- K1: ctx MLP — one 512-dot per wave, 840 waves --------------
__global__ __launch_bounds__(256) void k_ctx(const float* __restrict__ x,
                                             const float* __restrict__ cw,
                                             const float* __restrict__ cb,
                                             float* __restrict__ ws) {
  int lane = threadIdx.x & 63, wv = threadIdx.x >> 6;
  int row = blockIdx.x * 4 + wv;            // 0..839 (grid=210 exactly covers)
  int b = row / OUTF, i = row - b * OUTF;
  const float* wrow = cw + i * CTXD;
  const float* xr = x + b * CTXD;
  float acc = 0.f;
#pragma unroll
  for (int u = 0; u < CTXD; u += 64)
    acc = fmaf(wrow[u + lane], xr[u + lane], acc);
  acc = dpp_sum64(acc);
  if (lane == 63) ws[XT_OFF + row] = acc + cb[i];
}

// ---------------- K2: wf compute+store, Gram + per-rank sums -----------------
__global__ __launch_bounds__(256) void k_wfs(const float* __restrict__ wts,
                                             float* __restrict__ ws) {
  __shared__ float gl[BATCH * 96];
  __shared__ float gred[4][NACC];
  const float* xt = ws + XT_OFF;
  float* wfs = ws + WFS_OFF;
  int t = threadIdx.x;
  // per-block gating recompute (trivial): g = xt[:105]*tanh(xt[105:])
  for (int i = t; i < BATCH * 96; i += 256) {
    int b = i / 96, j = i - b * 96;
    gl[i] = xt[b * OUTF + j] * tanhf(xt[b * OUTF + 105 + j]);
  }
  __syncthreads();

  int p = blockIdx.x * 256 + t;             // 1 pixel per thread
  const float2* w2 = (const float2*)wts;
  float wf[BATCH][RANK];
#pragma unroll
  for (int k = 0; k < RANK; ++k) {
    // layout: page (k*4 + s*2 + comp), complex float2 per pixel
    float2 W0c0 = w2[((k * 4 + 0) << 18) + p];
    float2 W0c1 = w2[((k * 4 + 1) << 18) + p];
    float2 W1c0 = w2[((k * 4 + 2) << 18) + p];
    float2 W1c1 = w2[((k * 4 + 3) << 18) + p];
#pragma unroll
    for (int b = 0; b < BATCH; ++b) {
      const float* gb = gl + b * 96 + 12 * k;
      float zr0, zi0, zr1, zi1;
      {
        float c0 = gb[0] + 0.5f, c1 = gb[1], b0 = gb[4], b1 = gb[5];
        float s0 = gb[8] + 1.0f, s1 = gb[9];
        float dr = W1c0.x - W0c0.x, di = W1c0.y - W0c0.y;
        float lr = W0c0.x + c0 * dr - c1 * di;
        float li = W0c0.y + c0 * di + c1 * dr;
        zr0 = b0 + lr * s0 - li * s1;
        zi0 = b1 + lr * s1 + li * s0;
      }
      {
        float c0 = gb[2] + 0.5f, c1 = gb[3], b0 = gb[6], b1 = gb[7];
        float s0 = gb[10] + 1.0f, s1 = gb[11];
        float dr = W1c1.x - W0c1.x, di = W1c1.y - W0c1.y;
        float lr = W0c1.x + c0 * dr - c1 * di;
        float li = W0c1.y + c0 * di + c1 * dr;
        zr1 = b0 + lr * s0 - li * s1;
        zi1 = b1 + lr * s1 + li * s0;
      }
      float d2 = zr1 * zr1 + zi1 * zi1;
      float dn = sqrtf(fmaxf(d2, 1e-12f));
      float w = (zr0 * zr1 + zi0 * zi1) / dn;
      if (fabsf(w) < 1e-12f) w = (w > 0.f) ? 1e-12f : ((w < 0.f) ? -1e-12f : 0.f);
      wf[b][k] = w;
      wfs[((b * RANK + k) << 18) + p] = w;
    }
  }
  // reduce gram[4][36] (upper-tri incl diag) + S[4][8]
  int lane = t & 63, wv = t >> 6;
#pragma unroll
  for (int b = 0; b < BATCH; ++b) {
    int idx = b * 36;
#pragma unroll
    for (int r = 0; r < RANK; ++r)
#pragma unroll
      for (int s = r; s < RANK; ++s, ++idx) {
        float pr = dpp_sum64(wf[b][r] * wf[b][s]);
        if (lane == 63) gred[wv][idx] = pr;
      }
  }
#pragma unroll
  for (int b = 0; b < BATCH; ++b)
#pragma unroll
    for (int k = 0; k < RANK; ++k) {
      float pr = dpp_sum64(wf[b][k]);
      if (lane == 63) gred[wv][144 + b * 8 + k] = pr;
    }
  __syncthreads();
  if (t < NACC) {
    float s = gred[0][t] + gred[1][t] + gred[2][t] + gred[3][t];
    // 8-way replicated accumulators: same-address contention /8
    atomicAdd(ws + ACC_OFF + (blockIdx.x & (REP - 1)) * NACC + t, s);
  }
}

// ---------------- K3: analytic stats + output + noise ------------------------
__global__ __launch_bounds__(256) void k_out(const float* __restrict__ ws,
                                             float* __restrict__ out) {
  const float* xt = ws + XT_OFF;
  const float* wfs = ws + WFS_OFF;
  __shared__ float G[NACC];                  // [0:144) gram, [144:176) S
  __shared__ float n1[32], Ml[256], vv[32], scl[32], ca[4], wrl[BATCH][9];
  __shared__ float in2[32], mnv[32], sdv[32];
  int t = threadIdx.x;
  if (t < NACC) {
    float s = 0.f;
#pragma unroll
    for (int rep = 0; rep < REP; ++rep) s += ws[ACC_OFF + rep * NACC + t];
    G[t] = s;
  }
  if (t >= 192 && t < 192 + BATCH) {         // wr softmax (per-batch thread)
    int b = t - 192;
    float raw[9];
#pragma unroll
    for (int j = 0; j < 9; ++j)
      raw[j] = xt[b * OUTF + 96 + j] * tanhf(xt[b * OUTF + 201 + j]);
    raw[8] += 0.35355339059327373f;          // 1/sqrt(8)
    double ss = 0.0;
    for (int j = 0; j < 9; ++j) ss += (double)raw[j] * (double)raw[j];
    float n = fmaxf((float)sqrt(ss), 1e-12f);
    float y[9]; float m = -1e30f;
    for (int j = 0; j < 9; ++j) { y[j] = raw[j] / n; m = fmaxf(m, y[j]); }
    float e[9]; double se = 0.0;
    for (int j = 0; j < 9; ++j) { e[j] = expf(y[j] - m); se += (double)e[j]; }
    for (int j = 0; j < 9; ++j) wrl[b][j] = e[j] / (float)se;
  }
  __syncthreads();
  if (t < 32) {
    int b = t >> 3, k = t & 7;
    int di = k * 8 - (k * (k - 1)) / 2;
    n1[t] = fmaxf(sqrtf(G[b * 36 + di]), 1e-12f);
  }
  __syncthreads();
  {
    int b = t >> 6, k = (t >> 3) & 7, s = t & 7;
    float m;
    if (k == s) {
      m = 1.0f / n1[b * 8 + k];
    } else {
      int r0 = k < s ? k : s, s0 = k < s ? s : k;
      int gi = r0 * 8 - (r0 * (r0 - 1)) / 2 + (s0 - r0);
      float simv = G[b * 36 + gi] / (n1[b * 8 + k] * n1[b * 8 + s]);
      m = -0.0050507627227610544f * simv / n1[b * 8 + s];  // (0.1/sqrt(8))/7
    }
    Ml[t] = m;
  }
  __syncthreads();
  if (t < 32) {
    int b = t >> 3, k = t & 7;
    // sum = M.S ; sumsq = (M G M^T)_kk  — exact linear-algebra of the 2nd pass
    float sum = 0.f, sq = 0.f;
#pragma unroll
    for (int s = 0; s < 8; ++s) {
      float ms = Ml[b * 64 + k * 8 + s];
      sum = fmaf(ms, G[144 + b * 8 + s], sum);
#pragma unroll
      for (int u = 0; u < 8; ++u) {
        int r0 = s < u ? s : u, s0 = s < u ? u : s;
        int gi = r0 * 8 - (r0 * (r0 - 1)) / 2 + (s0 - r0);
        sq = fmaf(ms * Ml[b * 64 + k * 8 + u], G[b * 36 + gi], sq);
      }
    }
    float n2 = fmaxf(sqrtf(fmaxf(sq, 0.f)), 1e-12f);
    float mean = sum / n2 * (1.0f / NPIX);
    float sy2 = sq / (n2 * n2);
    float var = (sy2 - (float)NPIX * mean * mean) * (1.0f / (float)(NPIX - 1));
    var = fmaxf(var, 0.f);
    float sd = fmaxf(sqrtf(var), 1e-12f);
    in2[t] = 1.f / n2; mnv[t] = mean; sdv[t] = sd;
  }
  __syncthreads();
  if (t < 32) {
    int b = t >> 3, s = t & 7;
    float acc = 0.f;
#pragma unroll
    for (int k = 0; k < 8; ++k)
      acc += wrl[b][k] * Ml[b * 64 + k * 8 + s] * in2[b * 8 + k];
    vv[t] = acc;
    scl[t] = wrl[b][s] * 0.01f * sdv[t];
  }
  if (t < BATCH) {
    float a = 0.f;
#pragma unroll
    for (int k = 0; k < 8; ++k) a += wrl[t][k] * 0.01f * mnv[t * 8 + k];
    ca[t] = a;
  }
  __syncthreads();

  int p = blockIdx.x * 256 + t;
  float o[4];
#pragma unroll
  for (int b = 0; b < 4; ++b) {
    float acc = ca[b];
#pragma unroll
    for (int s = 0; s < 8; ++s)
      acc = fmaf(vv[b * 8 + s], wfs[((b * RANK + s) << 18) + p], acc);
    o[b] = acc;
  }
  // noise: flat j=(b*8+k)*NPIX+p over 2^23 elems; (j, j+2^22) share a threefry block
#pragma unroll
  for (int bk = 0; bk < 16; ++bk) {
    unsigned int i = ((unsigned int)bk << 18) + (unsigned int)p;
    unsigned int r0, r1;
    threefry2x32_pair(i, i + 0x400000u, &r0, &r1);
    int b2 = bk >> 3, k = bk & 7;
    o[b2]     += scl[b2 * 8 + k]       * fast_normal(r0);
    o[b2 + 2] += scl[(b2 + 2) * 8 + k] * fast_normal(r1);
  }
#pragma unroll
  for (int b = 0; b < 4; ++b) out[(b << 18) + p] = o[b];
}

extern "C" void kernel_launch(void* const* d_in, const int* in_sizes, int n_in,
                              void* d_out, int out_size, void* d_ws, size_t ws_size,
                              hipStream_t stream) {
  const float* x   = (const float*)d_in[0];
  const float* cw  = (const float*)d_in[1];
  const float* cb  = (const float*)d_in[2];
  const float* wts = (const float*)d_in[3];
  float* out = (float*)d_out;
  float* ws  = (float*)d_ws;

  hipMemsetAsync((char*)d_ws + ZERO_BYTE, 0, ZERO_LEN, stream);

  k_ctx <<<210,  256, 0, stream>>>(x, cw, cb, ws);
  k_wfs <<<1024, 256, 0, stream>>>(wts, ws);
  k_out <<<1024, 256, 0, stream>>>(ws, out);
}